// Round 5
// baseline (887.347 us; speedup 1.0000x reference)
//
#include <hip/hip_runtime.h>

#define B_  2
#define NH  16
#define S_  2048
#define D_  128
#define HID 2048

typedef _Float16 half_t;
typedef _Float16 f16x8 __attribute__((ext_vector_type(8)));
typedef _Float16 f16x4_t __attribute__((ext_vector_type(4)));
typedef float f32x4 __attribute__((ext_vector_type(4)));

__device__ __forceinline__ float fexp2(float x) { return __builtin_amdgcn_exp2f(x); }

// ---------------- fused fp32 -> fp16 convert ----------------
__global__ __launch_bounds__(256) void cvt_all(
    const float* __restrict__ x,  const float* __restrict__ wq, const float* __restrict__ wk,
    const float* __restrict__ wv, const float* __restrict__ wo, half_t* __restrict__ dst)
{
    long i = ((long)blockIdx.x * 256 + threadIdx.x) * 4;
    const float* src; long off;
    if (i < 8388608)       { src = x;  off = i; }
    else if (i < 12582912) { src = wq; off = i - 8388608; }
    else if (i < 16777216) { src = wk; off = i - 12582912; }
    else if (i < 20971520) { src = wv; off = i - 16777216; }
    else                   { src = wo; off = i - 20971520; }
    float4 v = *(const float4*)(src + off);
    f16x4_t h;
    h[0] = (half_t)v.x; h[1] = (half_t)v.y; h[2] = (half_t)v.z; h[3] = (half_t)v.w;
    *(f16x4_t*)(dst + i) = h;
}

// ---------------- fused QKV GEMM + RoPE (flatmm: direct-to-reg, no LDS, no barriers) ----------------
// 128x128 block tile, waves 2x2; wave rows wm*64+mt*16, cols wn*16+nt*32 (RoPE pairs in-lane).
__global__ __launch_bounds__(256, 3) void qkv_gemm(
    const half_t* __restrict__ xb,
    const half_t* __restrict__ wqb, const half_t* __restrict__ wkb, const half_t* __restrict__ wvb,
    const float* __restrict__ bq, const float* __restrict__ bk, const float* __restrict__ bv,
    const float* __restrict__ cosp, const float* __restrict__ sinp,
    half_t* __restrict__ qo, half_t* __restrict__ ko, half_t* __restrict__ vto)
{
    const int m0 = blockIdx.x * 128;
    const int n0 = blockIdx.y * 128;
    const int z  = blockIdx.z;
    const half_t* wb   = (z == 0) ? wqb : (z == 1) ? wkb : wvb;
    const float*  bias = (z == 0) ? bq  : (z == 1) ? bk  : bv;
    const int tid = threadIdx.x, wave = tid >> 6, lane = tid & 63;
    const int quad = lane >> 4, lrow = lane & 15;
    const int wm = wave >> 1, wn = wave & 1;

    const half_t* ap = xb + (size_t)(m0 + wm * 64 + lrow) * HID + quad * 8;
    const half_t* bp = wb + (size_t)(n0 + wn * 16 + lrow) * HID + quad * 8;

    f16x8 afr[2][4], bfr[2][4];
    f32x4 acc[4][4] = {};

#pragma unroll
    for (int mt = 0; mt < 4; mt++) afr[0][mt] = *(const f16x8*)(ap + (size_t)mt * 16 * HID);
#pragma unroll
    for (int nt = 0; nt < 4; nt++) bfr[0][nt] = *(const f16x8*)(bp + (size_t)nt * 32 * HID);

#pragma unroll 2
    for (int k0 = 0; k0 < HID - 32; k0 += 32) {
        const int p = (k0 >> 5) & 1, pn = p ^ 1;
#pragma unroll
        for (int mt = 0; mt < 4; mt++)
            afr[pn][mt] = *(const f16x8*)(ap + k0 + 32 + (size_t)mt * 16 * HID);
#pragma unroll
        for (int nt = 0; nt < 4; nt++)
            bfr[pn][nt] = *(const f16x8*)(bp + k0 + 32 + (size_t)nt * 32 * HID);
#pragma unroll
        for (int mt = 0; mt < 4; mt++)
#pragma unroll
            for (int nt = 0; nt < 4; nt++)
                acc[mt][nt] = __builtin_amdgcn_mfma_f32_16x16x32_f16(afr[p][mt], bfr[p][nt], acc[mt][nt], 0, 0, 0);
    }
#pragma unroll
    for (int mt = 0; mt < 4; mt++)
#pragma unroll
        for (int nt = 0; nt < 4; nt++)
            acc[mt][nt] = __builtin_amdgcn_mfma_f32_16x16x32_f16(afr[1][mt], bfr[1][nt], acc[mt][nt], 0, 0, 0);

    const int head = blockIdx.y;
    float bs_[4];
#pragma unroll
    for (int nt = 0; nt < 4; nt++) bs_[nt] = bias[n0 + nt * 32 + wn * 16 + lrow];
#pragma unroll
    for (int mt = 0; mt < 4; mt++) {
#pragma unroll
        for (int r = 0; r < 4; r++) {
            const int m  = m0 + wm * 64 + mt * 16 + quad * 4 + r;
            const int bb = m >> 11;
            const int st = m & (S_ - 1);
            float res[4];
#pragma unroll
            for (int nt = 0; nt < 4; nt++) res[nt] = acc[mt][nt][r] + bs_[nt];
            if (z < 2) {
                const float* cr = cosp + st * D_;
                const float* sr = sinp + st * D_;
#pragma unroll
                for (int pr = 0; pr < 2; pr++) {
                    const int dlo = pr * 32 + wn * 16 + lrow;
                    float cl = cr[dlo], sl = sr[dlo], ch = cr[dlo + 64], sh = sr[dlo + 64];
                    float lo = res[pr], hi = res[pr + 2];
                    res[pr]     = lo * cl - hi * sl;
                    res[pr + 2] = hi * ch + lo * sh;
                }
                half_t* dst = (z == 0 ? qo : ko) + ((size_t)(bb * NH + head) * S_ + st) * D_;
#pragma unroll
                for (int nt = 0; nt < 4; nt++) dst[nt * 32 + wn * 16 + lrow] = (half_t)res[nt];
            } else {
                half_t* dst = vto + (size_t)(bb * NH + head) * D_ * S_ + st;
#pragma unroll
                for (int nt = 0; nt < 4; nt++) dst[(size_t)(nt * 32 + wn * 16 + lrow) * S_] = (half_t)res[nt];
            }
        }
    }
}

// ---------------- flash attention: Q-tile 128, S^T softmax, direct K/V loads, ZERO barriers ----------------
#define PLD 72
__global__ __launch_bounds__(256, 2) void attn_kernel(
    const half_t* __restrict__ qb, const half_t* __restrict__ kb,
    const half_t* __restrict__ vtb, half_t* __restrict__ ob)
{
    __shared__ __align__(16) half_t ps[4 * 32 * PLD];  // 18 KB wave-private P (A-layout)
    const int head = blockIdx.y, b = blockIdx.z;
    const int bh = b * NH + head;
    const int tid = threadIdx.x, wave = tid >> 6, lane = tid & 63;
    const int quad = lane >> 4, lrow = lane & 15;
    const float SC = 0.08838834764831845f * 1.4426950408889634f;  // scale*log2(e)
    const int q0 = blockIdx.x * 128 + wave * 32;

    f16x8 qf[2][4];
#pragma unroll
    for (int mt = 0; mt < 2; mt++) {
        const half_t* qrow = qb + ((size_t)bh * S_ + q0 + mt * 16 + lrow) * D_;
#pragma unroll
        for (int kc = 0; kc < 4; kc++) {
            f16x8 v = *(const f16x8*)(qrow + kc * 32 + quad * 8);
#pragma unroll
            for (int j = 0; j < 8; j++) v[j] = (half_t)((float)v[j] * SC);
            qf[mt][kc] = v;
        }
    }

    const half_t* kbase = kb + (size_t)bh * S_ * D_;
    const half_t* vbase = vtb + (size_t)bh * D_ * S_;
    const int pbase = wave * 32 * PLD;

    float m_run[2] = {-1e30f, -1e30f}, l_run[2] = {0.f, 0.f};
    f32x4 o[2][8] = {};

    for (int kt = 0; kt < 32; kt++) {
        // S^T = K_tile . Q^T : lane holds q-row = lrow, k-col = nt*16+quad*4+r (in-lane)
        f32x4 st[2][4] = {};
#pragma unroll
        for (int nt = 0; nt < 4; nt++) {
            const half_t* krow = kbase + (size_t)(kt * 64 + nt * 16 + lrow) * D_ + quad * 8;
            f16x8 kf[4];
#pragma unroll
            for (int kc = 0; kc < 4; kc++) kf[kc] = *(const f16x8*)(krow + kc * 32);
#pragma unroll
            for (int kc = 0; kc < 4; kc++) {
                st[0][nt] = __builtin_amdgcn_mfma_f32_16x16x32_f16(kf[kc], qf[0][kc], st[0][nt], 0, 0, 0);
                st[1][nt] = __builtin_amdgcn_mfma_f32_16x16x32_f16(kf[kc], qf[1][kc], st[1][nt], 0, 0, 0);
            }
        }

        // online softmax: in-lane tree + 2 shuffles; packed b64 P stores (A-layout)
        bool upd = false;
        float alpha[2];
#pragma unroll
        for (int mt = 0; mt < 2; mt++) {
            float m01 = fmaxf(fmaxf(st[mt][0][0], st[mt][0][1]), fmaxf(st[mt][0][2], st[mt][0][3]));
            float m11 = fmaxf(fmaxf(st[mt][1][0], st[mt][1][1]), fmaxf(st[mt][1][2], st[mt][1][3]));
            float m21 = fmaxf(fmaxf(st[mt][2][0], st[mt][2][1]), fmaxf(st[mt][2][2], st[mt][2][3]));
            float m31 = fmaxf(fmaxf(st[mt][3][0], st[mt][3][1]), fmaxf(st[mt][3][2], st[mt][3][3]));
            float mx = fmaxf(fmaxf(m01, m11), fmaxf(m21, m31));
            mx = fmaxf(mx, __shfl_xor(mx, 16));
            mx = fmaxf(mx, __shfl_xor(mx, 32));
            const float mnew = fmaxf(m_run[mt], mx);
            alpha[mt] = fexp2(m_run[mt] - mnew);
            upd = upd || (mnew > m_run[mt]);
            m_run[mt] = mnew;
            float rs = 0.f;
#pragma unroll
            for (int nt = 0; nt < 4; nt++) {
                f16x4_t pk4;
#pragma unroll
                for (int r = 0; r < 4; r++) {
                    float p = fexp2(st[mt][nt][r] - mnew);
                    rs += p;
                    pk4[r] = (half_t)p;
                }
                *(f16x4_t*)&ps[pbase + (mt * 16 + lrow) * PLD + nt * 16 + quad * 4] = pk4;
            }
            rs += __shfl_xor(rs, 16);
            rs += __shfl_xor(rs, 32);
            l_run[mt] = l_run[mt] * alpha[mt] + rs;
        }
        if (__any(upd)) {
#pragma unroll
            for (int mt = 0; mt < 2; mt++) {
                float ab[4];
#pragma unroll
                for (int r = 0; r < 4; r++) ab[r] = __shfl(alpha[mt], quad * 4 + r, 16);
#pragma unroll
                for (int dt = 0; dt < 8; dt++)
#pragma unroll
                    for (int r = 0; r < 4; r++) o[mt][dt][r] *= ab[r];
            }
        }

        // O += P V  (V fragments direct from global: contiguous 16B in s)
#pragma unroll
        for (int kc2 = 0; kc2 < 2; kc2++) {
            f16x8 pf0 = *(const f16x8*)&ps[pbase + lrow * PLD + kc2 * 32 + quad * 8];
            f16x8 pf1 = *(const f16x8*)&ps[pbase + (16 + lrow) * PLD + kc2 * 32 + quad * 8];
            const half_t* vcol = vbase + kt * 64 + kc2 * 32 + quad * 8;
#pragma unroll
            for (int dt = 0; dt < 8; dt++) {
                f16x8 vf = *(const f16x8*)(vcol + (size_t)(dt * 16 + lrow) * S_);
                o[0][dt] = __builtin_amdgcn_mfma_f32_16x16x32_f16(pf0, vf, o[0][dt], 0, 0, 0);
                o[1][dt] = __builtin_amdgcn_mfma_f32_16x16x32_f16(pf1, vf, o[1][dt], 0, 0, 0);
            }
        }
    }

    // epilogue
#pragma unroll
    for (int mt = 0; mt < 2; mt++) {
        const float rl = 1.f / l_run[mt];
        float rb[4];
#pragma unroll
        for (int r = 0; r < 4; r++) rb[r] = __shfl(rl, quad * 4 + r, 16);
#pragma unroll
        for (int dt = 0; dt < 8; dt++) {
            const int d = dt * 16 + lrow;
#pragma unroll
            for (int r = 0; r < 4; r++) {
                const int row = q0 + mt * 16 + quad * 4 + r;
                ob[((size_t)b * S_ + row) * HID + head * D_ + d] = (half_t)(o[mt][dt][r] * rb[r]);
            }
        }
    }
}

// ---------------- output projection (flatmm, fp32 out) ----------------
__global__ __launch_bounds__(256, 3) void out_gemm(
    const half_t* __restrict__ ab, const half_t* __restrict__ wob, float* __restrict__ out)
{
    const int m0 = blockIdx.x * 128;
    const int n0 = blockIdx.y * 128;
    const int tid = threadIdx.x, wave = tid >> 6, lane = tid & 63;
    const int quad = lane >> 4, lrow = lane & 15;
    const int wm = wave >> 1, wn = wave & 1;

    const half_t* ap = ab  + (size_t)(m0 + wm * 64 + lrow) * HID + quad * 8;
    const half_t* bp = wob + (size_t)(n0 + wn * 16 + lrow) * HID + quad * 8;

    f16x8 afr[2][4], bfr[2][4];
    f32x4 acc[4][4] = {};

#pragma unroll
    for (int mt = 0; mt < 4; mt++) afr[0][mt] = *(const f16x8*)(ap + (size_t)mt * 16 * HID);
#pragma unroll
    for (int nt = 0; nt < 4; nt++) bfr[0][nt] = *(const f16x8*)(bp + (size_t)nt * 32 * HID);

#pragma unroll 2
    for (int k0 = 0; k0 < HID - 32; k0 += 32) {
        const int p = (k0 >> 5) & 1, pn = p ^ 1;
#pragma unroll
        for (int mt = 0; mt < 4; mt++)
            afr[pn][mt] = *(const f16x8*)(ap + k0 + 32 + (size_t)mt * 16 * HID);
#pragma unroll
        for (int nt = 0; nt < 4; nt++)
            bfr[pn][nt] = *(const f16x8*)(bp + k0 + 32 + (size_t)nt * 32 * HID);
#pragma unroll
        for (int mt = 0; mt < 4; mt++)
#pragma unroll
            for (int nt = 0; nt < 4; nt++)
                acc[mt][nt] = __builtin_amdgcn_mfma_f32_16x16x32_f16(afr[p][mt], bfr[p][nt], acc[mt][nt], 0, 0, 0);
    }
#pragma unroll
    for (int mt = 0; mt < 4; mt++)
#pragma unroll
        for (int nt = 0; nt < 4; nt++)
            acc[mt][nt] = __builtin_amdgcn_mfma_f32_16x16x32_f16(afr[1][mt], bfr[1][nt], acc[mt][nt], 0, 0, 0);

#pragma unroll
    for (int mt = 0; mt < 4; mt++)
#pragma unroll
        for (int r = 0; r < 4; r++) {
            const int m = m0 + wm * 64 + mt * 16 + quad * 4 + r;
#pragma unroll
            for (int nt = 0; nt < 4; nt++)
                out[(size_t)m * HID + n0 + nt * 32 + wn * 16 + lrow] = acc[mt][nt][r];
        }
}

extern "C" void kernel_launch(void* const* d_in, const int* in_sizes, int n_in,
                              void* d_out, int out_size, void* d_ws, size_t ws_size,
                              hipStream_t stream)
{
    const float* x    = (const float*)d_in[0];
    const float* cosp = (const float*)d_in[1];
    const float* sinp = (const float*)d_in[2];
    const float* wq   = (const float*)d_in[3];
    const float* bq   = (const float*)d_in[4];
    const float* wk   = (const float*)d_in[5];
    const float* bk   = (const float*)d_in[6];
    const float* wv   = (const float*)d_in[7];
    const float* bv   = (const float*)d_in[8];
    const float* wo   = (const float*)d_in[9];
    float* out = (float*)d_out;

    half_t* w   = (half_t*)d_ws;
    half_t* xb  = w;
    half_t* wqb = xb  + 8388608;
    half_t* wkb = wqb + 4194304;
    half_t* wvb = wkb + 4194304;
    half_t* wob = wvb + 4194304;
    half_t* qo  = wob + 4194304;        // (b,h,s,d)
    half_t* ko  = qo  + 8388608;        // (b,h,s,d)
    half_t* vto = ko  + 8388608;        // (b,h,d,s)
    half_t* ob  = vto + 8388608;        // (b,s,h*d)

    cvt_all<<<24576, 256, 0, stream>>>(x, wq, wk, wv, wo, xb);
    qkv_gemm<<<dim3(32, 16, 3), 256, 0, stream>>>(xb, wqb, wkb, wvb, bq, bk, bv,
                                                  cosp, sinp, qo, ko, vto);
    attn_kernel<<<dim3(16, 16, 2), 256, 0, stream>>>(qo, ko, vto, ob);
    out_gemm<<<dim3(32, 16), 256, 0, stream>>>(ob, wob, out);
}

// Round 6
// 459.245 us; speedup vs baseline: 1.9322x; 1.9322x over previous
//
#include <hip/hip_runtime.h>

#define B_  2
#define NH  16
#define S_  2048
#define D_  128
#define HID 2048

typedef _Float16 half_t;
typedef _Float16 f16x8 __attribute__((ext_vector_type(8)));
typedef _Float16 f16x4_t __attribute__((ext_vector_type(4)));
typedef float f32x4 __attribute__((ext_vector_type(4)));

__device__ __forceinline__ void glds16(const half_t* g, half_t* l) {
    __builtin_amdgcn_global_load_lds(
        (const __attribute__((address_space(1))) void*)g,
        (__attribute__((address_space(3))) void*)l, 16, 0, 0);
}
__device__ __forceinline__ float fexp2(float x) { return __builtin_amdgcn_exp2f(x); }

// ---------------- fused fp32 -> fp16 convert ----------------
__global__ __launch_bounds__(256) void cvt_all(
    const float* __restrict__ x,  const float* __restrict__ wq, const float* __restrict__ wk,
    const float* __restrict__ wv, const float* __restrict__ wo, half_t* __restrict__ dst)
{
    long i = ((long)blockIdx.x * 256 + threadIdx.x) * 4;
    const float* src; long off;
    if (i < 8388608)       { src = x;  off = i; }
    else if (i < 12582912) { src = wq; off = i - 8388608; }
    else if (i < 16777216) { src = wk; off = i - 12582912; }
    else if (i < 20971520) { src = wv; off = i - 16777216; }
    else                   { src = wo; off = i - 20971520; }
    float4 v = *(const float4*)(src + off);
    f16x4_t h;
    h[0] = (half_t)v.x; h[1] = (half_t)v.y; h[2] = (half_t)v.z; h[3] = (half_t)v.w;
    *(f16x4_t*)(dst + i) = h;
}

// ---------------- fused QKV GEMM + RoPE (m97 structure, BK=64, swizzled LDS) ----------------
// 128x128 tile, BK=64, global_load_lds(16B). Wave (wm,wn): rows wm*64+mt*16, cols wn*16+nt*32.
__global__ __launch_bounds__(256, 3) void qkv_gemm(
    const half_t* __restrict__ xb,
    const half_t* __restrict__ wqb, const half_t* __restrict__ wkb, const half_t* __restrict__ wvb,
    const float* __restrict__ bq, const float* __restrict__ bk, const float* __restrict__ bv,
    const float* __restrict__ cosp, const float* __restrict__ sinp,
    half_t* __restrict__ qo, half_t* __restrict__ ko, half_t* __restrict__ vto)
{
    __shared__ __align__(16) half_t As[128 * 64];   // 16 KB
    __shared__ __align__(16) half_t Bs[128 * 64];   // 16 KB
    const int m0 = blockIdx.x * 128;
    const int n0 = blockIdx.y * 128;
    const int z  = blockIdx.z;
    const half_t* wb   = (z == 0) ? wqb : (z == 1) ? wkb : wvb;
    const float*  bias = (z == 0) ? bq  : (z == 1) ? bk  : bv;
    const int tid = threadIdx.x, wave = tid >> 6, lane = tid & 63;
    const int quad = lane >> 4, lrow = lane & 15;
    const int wm = wave >> 1, wn = wave & 1;

    // staging: wave w issue i covers rows w*32+i*8..+8; lane -> row +(lane>>3), chunk pos lane&7
    int srow[4]; const half_t *aga[4], *bga[4]; half_t *ald[4], *bld[4];
#pragma unroll
    for (int i = 0; i < 4; i++) {
        const int row = wave * 32 + i * 8 + (lane >> 3);
        const int c   = ((lane & 7) ^ (row & 7)) * 8;       // source k-chunk (swizzle inverse)
        srow[i] = row;
        aga[i] = xb + (size_t)(m0 + row) * HID + c;
        bga[i] = wb + (size_t)(n0 + row) * HID + c;
        ald[i] = &As[(wave * 32 + i * 8) * 64];
        bld[i] = &Bs[(wave * 32 + i * 8) * 64];
    }

    f32x4 acc[4][4] = {};

    for (int k0 = 0; k0 < HID; k0 += 64) {
        __syncthreads();
#pragma unroll
        for (int i = 0; i < 4; i++) {
            glds16(aga[i] + k0, ald[i]);
            glds16(bga[i] + k0, bld[i]);
        }
        __syncthreads();
#pragma unroll
        for (int kc = 0; kc < 2; kc++) {
            f16x8 af[4], bf[4];
#pragma unroll
            for (int mt = 0; mt < 4; mt++) {
                const int ra = wm * 64 + mt * 16 + lrow;
                const int pa = (kc * 4 + quad) ^ (ra & 7);
                af[mt] = *(const f16x8*)&As[ra * 64 + pa * 8];
            }
#pragma unroll
            for (int nt = 0; nt < 4; nt++) {
                const int rb = wn * 16 + nt * 32 + lrow;
                const int pb = (kc * 4 + quad) ^ (rb & 7);
                bf[nt] = *(const f16x8*)&Bs[rb * 64 + pb * 8];
            }
#pragma unroll
            for (int mt = 0; mt < 4; mt++)
#pragma unroll
                for (int nt = 0; nt < 4; nt++)
                    acc[mt][nt] = __builtin_amdgcn_mfma_f32_16x16x32_f16(af[mt], bf[nt], acc[mt][nt], 0, 0, 0);
        }
    }

    const int head = blockIdx.y;
    float bs_[4];
#pragma unroll
    for (int nt = 0; nt < 4; nt++) bs_[nt] = bias[n0 + nt * 32 + wn * 16 + lrow];
#pragma unroll
    for (int mt = 0; mt < 4; mt++) {
#pragma unroll
        for (int r = 0; r < 4; r++) {
            const int m  = m0 + wm * 64 + mt * 16 + quad * 4 + r;
            const int bb = m >> 11;
            const int st = m & (S_ - 1);
            float res[4];
#pragma unroll
            for (int nt = 0; nt < 4; nt++) res[nt] = acc[mt][nt][r] + bs_[nt];
            if (z < 2) {
                const float* cr = cosp + st * D_;
                const float* sr = sinp + st * D_;
#pragma unroll
                for (int pr = 0; pr < 2; pr++) {
                    const int dlo = pr * 32 + wn * 16 + lrow;
                    float cl = cr[dlo], sl = sr[dlo], ch = cr[dlo + 64], sh = sr[dlo + 64];
                    float lo = res[pr], hi = res[pr + 2];
                    res[pr]     = lo * cl - hi * sl;
                    res[pr + 2] = hi * ch + lo * sh;
                }
                half_t* dst = (z == 0 ? qo : ko) + ((size_t)(bb * NH + head) * S_ + st) * D_;
#pragma unroll
                for (int nt = 0; nt < 4; nt++) dst[nt * 32 + wn * 16 + lrow] = (half_t)res[nt];
            } else {
                half_t* dst = vto + (size_t)(bb * NH + head) * D_ * S_ + st;
#pragma unroll
                for (int nt = 0; nt < 4; nt++) dst[(size_t)(nt * 32 + wn * 16 + lrow) * S_] = (half_t)res[nt];
            }
        }
    }
}

// ---------------- flash attention: Q-tile 128 (wave owns 32 rows), S^T softmax ----------------
#define PLD 72
__global__ __launch_bounds__(256, 3) void attn_kernel(
    const half_t* __restrict__ qb, const half_t* __restrict__ kb,
    const half_t* __restrict__ vtb, half_t* __restrict__ ob)
{
    __shared__ __align__(16) half_t ks[64 * 128];      // 16 KB swizzled
    __shared__ __align__(16) half_t vs[128 * 64];      // 16 KB swizzled
    __shared__ __align__(16) half_t ps[4 * 32 * PLD];  // 18 KB wave-private P (A-layout)
    const int head = blockIdx.y, b = blockIdx.z;
    const int bh = b * NH + head;
    const int tid = threadIdx.x, wave = tid >> 6, lane = tid & 63;
    const int quad = lane >> 4, lrow = lane & 15;
    const float SC = 0.08838834764831845f * 1.4426950408889634f;  // scale*log2(e)
    const int q0 = blockIdx.x * 128 + wave * 32;

    // Q fragments, pre-scaled (used as MFMA *B* operand)
    f16x8 qf[2][4];
#pragma unroll
    for (int mt = 0; mt < 2; mt++) {
        const half_t* qrow = qb + ((size_t)bh * S_ + q0 + mt * 16 + lrow) * D_;
#pragma unroll
        for (int kc = 0; kc < 4; kc++) {
            f16x8 v = *(const f16x8*)(qrow + kc * 32 + quad * 8);
#pragma unroll
            for (int j = 0; j < 8; j++) v[j] = (half_t)((float)v[j] * SC);
            qf[mt][kc] = v;
        }
    }

    const half_t* kbase = kb + (size_t)bh * S_ * D_;
    const half_t* vbase = vtb + (size_t)bh * D_ * S_;
    const int pbase = wave * 32 * PLD;

    float m_run[2] = {-1e30f, -1e30f}, l_run[2] = {0.f, 0.f};
    f32x4 o[2][8] = {};

    for (int kt = 0; kt < 32; kt++) {
        __syncthreads();
#pragma unroll
        for (int i = 0; i < 4; i++) {
            const int rk = wave * 16 + i * 4 + (lane >> 4);
            const int ck = (((lane & 15) - (rk & 7)) & 15) * 8;
            glds16(kbase + (size_t)(kt * 64 + rk) * D_ + ck, &ks[(wave * 16 + i * 4) * 128]);
            const int rv = wave * 32 + i * 8 + (lane >> 3);
            const int cv = (((lane & 7) - (rv & 7)) & 7) * 8;
            glds16(vbase + (size_t)rv * S_ + kt * 64 + cv, &vs[(wave * 32 + i * 8) * 64]);
        }
        __syncthreads();

        // S^T = K_tile . Q^T : lane holds q-row = lrow, k-col = nt*16+quad*4+r (in-lane)
        f32x4 st[2][4] = {};
#pragma unroll
        for (int nt = 0; nt < 4; nt++) {
            const int rk2 = nt * 16 + lrow;
#pragma unroll
            for (int kc = 0; kc < 4; kc++) {
                const int pk = (kc * 4 + quad + (rk2 & 7)) & 15;
                f16x8 kf = *(const f16x8*)&ks[rk2 * 128 + pk * 8];
                st[0][nt] = __builtin_amdgcn_mfma_f32_16x16x32_f16(kf, qf[0][kc], st[0][nt], 0, 0, 0);
                st[1][nt] = __builtin_amdgcn_mfma_f32_16x16x32_f16(kf, qf[1][kc], st[1][nt], 0, 0, 0);
            }
        }

        // online softmax: in-lane tree + 2 shuffles; packed b64 P stores (A-layout)
        bool upd = false;
        float alpha[2];
#pragma unroll
        for (int mt = 0; mt < 2; mt++) {
            float m01 = fmaxf(fmaxf(st[mt][0][0], st[mt][0][1]), fmaxf(st[mt][0][2], st[mt][0][3]));
            float m11 = fmaxf(fmaxf(st[mt][1][0], st[mt][1][1]), fmaxf(st[mt][1][2], st[mt][1][3]));
            float m21 = fmaxf(fmaxf(st[mt][2][0], st[mt][2][1]), fmaxf(st[mt][2][2], st[mt][2][3]));
            float m31 = fmaxf(fmaxf(st[mt][3][0], st[mt][3][1]), fmaxf(st[mt][3][2], st[mt][3][3]));
            float mx = fmaxf(fmaxf(m01, m11), fmaxf(m21, m31));
            mx = fmaxf(mx, __shfl_xor(mx, 16));
            mx = fmaxf(mx, __shfl_xor(mx, 32));
            const float mnew = fmaxf(m_run[mt], mx);
            alpha[mt] = fexp2(m_run[mt] - mnew);
            upd = upd || (mnew > m_run[mt]);
            m_run[mt] = mnew;
            float rs = 0.f;
#pragma unroll
            for (int nt = 0; nt < 4; nt++) {
                f16x4_t pk4;
#pragma unroll
                for (int r = 0; r < 4; r++) {
                    float p = fexp2(st[mt][nt][r] - mnew);
                    rs += p;
                    pk4[r] = (half_t)p;
                }
                *(f16x4_t*)&ps[pbase + (mt * 16 + lrow) * PLD + nt * 16 + quad * 4] = pk4;
            }
            rs += __shfl_xor(rs, 16);
            rs += __shfl_xor(rs, 32);
            l_run[mt] = l_run[mt] * alpha[mt] + rs;
        }
        if (__any(upd)) {
#pragma unroll
            for (int mt = 0; mt < 2; mt++) {
                float ab[4];
#pragma unroll
                for (int r = 0; r < 4; r++) ab[r] = __shfl(alpha[mt], quad * 4 + r, 16);
#pragma unroll
                for (int dt = 0; dt < 8; dt++)
#pragma unroll
                    for (int r = 0; r < 4; r++) o[mt][dt][r] *= ab[r];
            }
        }

        // O += P V
#pragma unroll
        for (int kc2 = 0; kc2 < 2; kc2++) {
            f16x8 pf0 = *(const f16x8*)&ps[pbase + lrow * PLD + kc2 * 32 + quad * 8];
            f16x8 pf1 = *(const f16x8*)&ps[pbase + (16 + lrow) * PLD + kc2 * 32 + quad * 8];
#pragma unroll
            for (int dt = 0; dt < 8; dt++) {
                const int rv2 = dt * 16 + lrow;
                const int pv = (kc2 * 4 + quad + (rv2 & 7)) & 7;
                f16x8 vf = *(const f16x8*)&vs[rv2 * 64 + pv * 8];
                o[0][dt] = __builtin_amdgcn_mfma_f32_16x16x32_f16(pf0, vf, o[0][dt], 0, 0, 0);
                o[1][dt] = __builtin_amdgcn_mfma_f32_16x16x32_f16(pf1, vf, o[1][dt], 0, 0, 0);
            }
        }
    }

    // epilogue
#pragma unroll
    for (int mt = 0; mt < 2; mt++) {
        const float rl = 1.f / l_run[mt];
        float rb[4];
#pragma unroll
        for (int r = 0; r < 4; r++) rb[r] = __shfl(rl, quad * 4 + r, 16);
#pragma unroll
        for (int dt = 0; dt < 8; dt++) {
            const int d = dt * 16 + lrow;
#pragma unroll
            for (int r = 0; r < 4; r++) {
                const int row = q0 + mt * 16 + quad * 4 + r;
                ob[((size_t)b * S_ + row) * HID + head * D_ + d] = (half_t)(o[mt][dt][r] * rb[r]);
            }
        }
    }
}

// ---------------- output projection (BK=64, fp32 out) ----------------
__global__ __launch_bounds__(256, 3) void out_gemm(
    const half_t* __restrict__ ab, const half_t* __restrict__ wob, float* __restrict__ out)
{
    __shared__ __align__(16) half_t As[128 * 64];
    __shared__ __align__(16) half_t Bs[128 * 64];
    const int m0 = blockIdx.x * 128;
    const int n0 = blockIdx.y * 128;
    const int tid = threadIdx.x, wave = tid >> 6, lane = tid & 63;
    const int quad = lane >> 4, lrow = lane & 15;
    const int wm = wave >> 1, wn = wave & 1;

    const half_t *aga[4], *bga[4]; half_t *ald[4], *bld[4];
#pragma unroll
    for (int i = 0; i < 4; i++) {
        const int row = wave * 32 + i * 8 + (lane >> 3);
        const int c   = ((lane & 7) ^ (row & 7)) * 8;
        aga[i] = ab  + (size_t)(m0 + row) * HID + c;
        bga[i] = wob + (size_t)(n0 + row) * HID + c;
        ald[i] = &As[(wave * 32 + i * 8) * 64];
        bld[i] = &Bs[(wave * 32 + i * 8) * 64];
    }

    f32x4 acc[4][4] = {};

    for (int k0 = 0; k0 < HID; k0 += 64) {
        __syncthreads();
#pragma unroll
        for (int i = 0; i < 4; i++) {
            glds16(aga[i] + k0, ald[i]);
            glds16(bga[i] + k0, bld[i]);
        }
        __syncthreads();
#pragma unroll
        for (int kc = 0; kc < 2; kc++) {
            f16x8 af[4], bf[4];
#pragma unroll
            for (int mt = 0; mt < 4; mt++) {
                const int ra = wm * 64 + mt * 16 + lrow;
                const int pa = (kc * 4 + quad) ^ (ra & 7);
                af[mt] = *(const f16x8*)&As[ra * 64 + pa * 8];
            }
#pragma unroll
            for (int nt = 0; nt < 4; nt++) {
                const int rb = wn * 16 + nt * 32 + lrow;
                const int pb = (kc * 4 + quad) ^ (rb & 7);
                bf[nt] = *(const f16x8*)&Bs[rb * 64 + pb * 8];
            }
#pragma unroll
            for (int mt = 0; mt < 4; mt++)
#pragma unroll
                for (int nt = 0; nt < 4; nt++)
                    acc[mt][nt] = __builtin_amdgcn_mfma_f32_16x16x32_f16(af[mt], bf[nt], acc[mt][nt], 0, 0, 0);
        }
    }

#pragma unroll
    for (int mt = 0; mt < 4; mt++)
#pragma unroll
        for (int r = 0; r < 4; r++) {
            const int m = m0 + wm * 64 + mt * 16 + quad * 4 + r;
#pragma unroll
            for (int nt = 0; nt < 4; nt++)
                out[(size_t)m * HID + n0 + nt * 32 + wn * 16 + lrow] = acc[mt][nt][r];
        }
}

extern "C" void kernel_launch(void* const* d_in, const int* in_sizes, int n_in,
                              void* d_out, int out_size, void* d_ws, size_t ws_size,
                              hipStream_t stream)
{
    const float* x    = (const float*)d_in[0];
    const float* cosp = (const float*)d_in[1];
    const float* sinp = (const float*)d_in[2];
    const float* wq   = (const float*)d_in[3];
    const float* bq   = (const float*)d_in[4];
    const float* wk   = (const float*)d_in[5];
    const float* bk   = (const float*)d_in[6];
    const float* wv   = (const float*)d_in[7];
    const float* bv   = (const float*)d_in[8];
    const float* wo   = (const float*)d_in[9];
    float* out = (float*)d_out;

    half_t* w   = (half_t*)d_ws;
    half_t* xb  = w;
    half_t* wqb = xb  + 8388608;
    half_t* wkb = wqb + 4194304;
    half_t* wvb = wkb + 4194304;
    half_t* wob = wvb + 4194304;
    half_t* qo  = wob + 4194304;        // (b,h,s,d)
    half_t* ko  = qo  + 8388608;        // (b,h,s,d)
    half_t* vto = ko  + 8388608;        // (b,h,d,s)
    half_t* ob  = vto + 8388608;        // (b,s,h*d)

    cvt_all<<<24576, 256, 0, stream>>>(x, wq, wk, wv, wo, xb);
    qkv_gemm<<<dim3(32, 16, 3), 256, 0, stream>>>(xb, wqb, wkb, wvb, bq, bk, bv,
                                                  cosp, sinp, qo, ko, vto);
    attn_kernel<<<dim3(16, 16, 2), 256, 0, stream>>>(qo, ko, vto, ob);
    out_gemm<<<dim3(32, 16), 256, 0, stream>>>(ob, wob, out);
}